// Round 1
// baseline (66.211 us; speedup 1.0000x reference)
//
#include <hip/hip_runtime.h>
#include <hip/hip_bf16.h>

// Problem constants (B=4, T=4096, C=2048, E=64)
#define N_TOK   16384
#define C_DIM   2048
#define E_DIM   64
#define P_OFF   (N_TOK * E_DIM)        // 1048576 — end of probs section
#define FB_OFF  P_OFF                  // fallback_count scalar
#define LG_OFF  (P_OFF + 1)            // logits section
#define AM_OFF  (2 * P_OFF + 1)        // activation_mask section

typedef __attribute__((ext_vector_type(8))) short bf16x8;  // 8 bf16 in 4 VGPRs
typedef __attribute__((ext_vector_type(4))) float f32x4;

static __device__ __forceinline__ unsigned short f2bf_rtn(float f) {
    unsigned u = __float_as_uint(f);
    unsigned r = u + 0x7FFFu + ((u >> 16) & 1u);   // round-to-nearest-even
    return (unsigned short)(r >> 16);
}

// ---------------------------------------------------------------------------
// Kernel 1: prepack sim_matrix [2048,64] f32 -> bf16 hi/lo fragments in d_ws,
// in the exact linear order the main kernel's global_load_lds stages per
// 64-k tile:  stage s: [kk(2)][hl(2)][nb(4)][lane(64)][i(8)]  (8192 bf16).
// Fragment content for lane l, elem i: sim[kt*32 + (l>>4)*8 + i][nb*16 + (l&15)]
// Also zero-initializes the fallback counter in d_out.
// ---------------------------------------------------------------------------
__global__ void gating_prepack(const float* __restrict__ sim,
                               unsigned short* __restrict__ Bpk,
                               float* __restrict__ out) {
    int tid = blockIdx.x * 256 + threadIdx.x;
    if (tid == 0) out[FB_OFF] = 0.0f;
    if (tid >= C_DIM * E_DIM) return;
    int k = tid >> 6;
    int e = tid & 63;
    float v = sim[tid];                       // sim[k*64 + e]
    unsigned short hi = f2bf_rtn(v);
    float hif = __uint_as_float(((unsigned)hi) << 16);
    unsigned short lo = f2bf_rtn(v - hif);
    int s  = k >> 6;
    int kk = (k >> 5) & 1;
    int gr = (k >> 3) & 3;
    int i  = k & 7;
    int lane = gr * 16 + (e & 15);
    int nb   = e >> 4;
    int base = s * 8192 + ((kk * 2 + 0) * 4 + nb) * 512 + lane * 8 + i;
    Bpk[base]        = hi;   // hl = 0
    Bpk[base + 2048] = lo;   // hl = 1 -> +4*512
}

// ---------------------------------------------------------------------------
// Kernel 2: fused affinity-GEMM (split-bf16 MFMA) + gating epilogue.
// Grid 256 x 256 threads (4 waves). Wave w: tokens blk*64 + w*16 .. +15,
// all 64 experts. A loaded global->reg (f32->bf16 hi/lo in-register).
// B double-buffered in LDS via global_load_lds from the prepacked buffer.
// ---------------------------------------------------------------------------
__global__ __launch_bounds__(256)
void gating_main(const float* __restrict__ x,
                 const unsigned short* __restrict__ Bpk,
                 const float* __restrict__ gates,
                 float* __restrict__ out) {
    __shared__ unsigned short Blds[2][8192];   // 2 x 16 KB

    const int tid = threadIdx.x;
    const int l   = tid & 63;
    const int w   = tid >> 6;
    const int blk = blockIdx.x;
    const int row0 = blk * 64 + w * 16;
    const int g    = l >> 4;          // k-slot group
    const int e0   = l & 15;
    const float* xr = x + (size_t)(row0 + e0) * C_DIM;   // A row for this lane

    f32x4 acc[4];
#pragma unroll
    for (int nb = 0; nb < 4; ++nb) acc[nb] = (f32x4)0.0f;

    // ---- stage helper: 16 KB, 4 x 16B per thread, linear LDS dest ----
    auto stage = [&](int s, int buf) {
        const unsigned short* gp = Bpk + s * 8192;
#pragma unroll
        for (int j = 0; j < 4; ++j) {
            __builtin_amdgcn_global_load_lds(
                (const __attribute__((address_space(1))) unsigned int*)(gp + j * 2048 + tid * 8),
                (__attribute__((address_space(3))) unsigned int*)(&Blds[buf][j * 2048 + tid * 8]),
                16, 0, 0);
        }
    };

    stage(0, 0);
    __syncthreads();
    int cur = 0;

    for (int s = 0; s < 32; ++s) {
        if (s + 1 < 32) stage(s + 1, cur ^ 1);
#pragma unroll
        for (int kk = 0; kk < 2; ++kk) {
            const float* ap = xr + s * 64 + kk * 32 + g * 8;
            float4 a0 = *(const float4*)ap;
            float4 a1 = *(const float4*)(ap + 4);
            float av[8] = {a0.x, a0.y, a0.z, a0.w, a1.x, a1.y, a1.z, a1.w};
            bf16x8 ah, al_;
#pragma unroll
            for (int i = 0; i < 8; ++i) {
                unsigned short h = f2bf_rtn(av[i]);
                float hf = __uint_as_float(((unsigned)h) << 16);
                unsigned short lo = f2bf_rtn(av[i] - hf);
                ah[i]  = (short)h;
                al_[i] = (short)lo;
            }
#pragma unroll
            for (int nb = 0; nb < 4; ++nb) {
                bf16x8 bh = *(const bf16x8*)(&Blds[cur][(kk * 8 + nb) * 512 + l * 8]);
                bf16x8 bl = *(const bf16x8*)(&Blds[cur][(kk * 8 + 4 + nb) * 512 + l * 8]);
                acc[nb] = __builtin_amdgcn_mfma_f32_16x16x32_bf16(ah, bh, acc[nb], 0, 0, 0);
                acc[nb] = __builtin_amdgcn_mfma_f32_16x16x32_bf16(ah, bl, acc[nb], 0, 0, 0);
                acc[nb] = __builtin_amdgcn_mfma_f32_16x16x32_bf16(al_, bh, acc[nb], 0, 0, 0);
            }
        }
        __syncthreads();
        cur ^= 1;
    }

    // ---- epilogue ----
    float sig[4];
#pragma unroll
    for (int nb = 0; nb < 4; ++nb)
        sig[nb] = 1.0f / (1.0f + expf(-gates[nb * 16 + e0]));

#pragma unroll
    for (int r = 0; r < 4; ++r) {
        const int t = row0 + g * 4 + r;      // token (C/D row = (lane>>4)*4 + reg)
        float lg[4];
        bool  act[4];
        int   lcnt = 0;
        float lmax = -3.4e38f;
#pragma unroll
        for (int nb = 0; nb < 4; ++nb) {
            lg[nb]  = acc[nb][r] - sig[nb];
            act[nb] = lg[nb] > 0.0f;
            if (act[nb]) { lcnt++; lmax = fmaxf(lmax, lg[nb]); }
        }
        int cnt = lcnt;
        float mx = lmax;
#pragma unroll
        for (int m = 1; m < 16; m <<= 1) {
            cnt += __shfl_xor(cnt, m, 16);
            mx   = fmaxf(mx, __shfl_xor(mx, m, 16));
        }

        float p[4], am[4];
        if (cnt > 0) {
            float ex[4], ls = 0.0f;
#pragma unroll
            for (int nb = 0; nb < 4; ++nb) {
                ex[nb] = act[nb] ? expf(lg[nb] - mx) : 0.0f;
                ls += ex[nb];
            }
            float Z = ls;
#pragma unroll
            for (int m = 1; m < 16; m <<= 1) Z += __shfl_xor(Z, m, 16);
            float rz = 1.0f / Z;
#pragma unroll
            for (int nb = 0; nb < 4; ++nb) {
                p[nb]  = ex[nb] * rz;
                am[nb] = act[nb] ? 1.0f : 0.0f;
            }
        } else {
            // fallback: top-32 of the 64 logits (ties -> lower expert index).
            // All logits <= 0 here, so probs are uniform 1/32 over the set.
            unsigned selm = 0;
            for (int it = 0; it < 32; ++it) {
                float bv = -3.4e38f;
                int   bi = 127;
#pragma unroll
                for (int nb = 0; nb < 4; ++nb) {
                    if (!((selm >> nb) & 1)) {
                        float v = lg[nb];
                        int   e = nb * 16 + e0;
                        if (v > bv || (v == bv && e < bi)) { bv = v; bi = e; }
                    }
                }
#pragma unroll
                for (int m = 1; m < 16; m <<= 1) {
                    float ov = __shfl_xor(bv, m, 16);
                    int   oi = __shfl_xor(bi, m, 16);
                    if (ov > bv || (ov == bv && oi < bi)) { bv = ov; bi = oi; }
                }
                if ((bi & 15) == e0) selm |= 1u << (bi >> 4);
            }
#pragma unroll
            for (int nb = 0; nb < 4; ++nb) {
                bool s_ = (selm >> nb) & 1;
                p[nb]  = s_ ? (1.0f / 32.0f) : 0.0f;
                am[nb] = s_ ? 1.0f : 0.0f;
            }
            if (e0 == 0) atomicAdd(&out[FB_OFF], 1.0f);
        }

#pragma unroll
        for (int nb = 0; nb < 4; ++nb) {
            int idx = t * 64 + nb * 16 + e0;
            out[idx]          = p[nb];
            out[LG_OFF + idx] = lg[nb];
            out[AM_OFF + idx] = am[nb];
        }
    }
}

// ---------------------------------------------------------------------------
extern "C" void kernel_launch(void* const* d_in, const int* in_sizes, int n_in,
                              void* d_out, int out_size, void* d_ws, size_t ws_size,
                              hipStream_t stream) {
    const float* x     = (const float*)d_in[0];   // [4,4096,2048] f32
    const float* sim   = (const float*)d_in[1];   // [2048,64] f32
    const float* gates = (const float*)d_in[2];   // [64] f32
    float* out = (float*)d_out;
    unsigned short* Bpk = (unsigned short*)d_ws;  // 512 KB prepacked B (hi/lo)

    gating_prepack<<<512, 256, 0, stream>>>(sim, Bpk, out);
    gating_main<<<256, 256, 0, stream>>>(x, Bpk, gates, out);
}

// Round 2
// 46.794 us; speedup vs baseline: 1.4149x; 1.4149x over previous
//
#include <hip/hip_runtime.h>
#include <hip/hip_bf16.h>

// Problem constants (B=4, T=4096, C=2048, E=64)
#define N_TOK   16384
#define C_DIM   2048
#define E_DIM   64
#define P_OFF   (N_TOK * E_DIM)        // 1048576 — end of probs section
#define FB_OFF  P_OFF                  // fallback_count scalar
#define LG_OFF  (P_OFF + 1)            // logits section
#define AM_OFF  (2 * P_OFF + 1)        // activation_mask section

typedef __attribute__((ext_vector_type(8))) short bf16x8;  // 8 bf16 in 4 VGPRs
typedef __attribute__((ext_vector_type(4))) float f32x4;

static __device__ __forceinline__ unsigned short f2bf_rtn(float f) {
    unsigned u = __float_as_uint(f);
    unsigned r = u + 0x7FFFu + ((u >> 16) & 1u);   // round-to-nearest-even
    return (unsigned short)(r >> 16);
}

// ---------------------------------------------------------------------------
// Kernel 1: prepack sim_matrix [2048,64] f32 -> bf16 hi/lo fragments in d_ws.
// Stage s (64 k-values): [kk(2)][hl(2)][nb(4)][lane(64)][i(8)] shorts (8192).
// Fragment content: lane l, elem i -> sim[s*64 + kk*32 + (l>>4)*8 + i][nb*16 + (l&15)]
// Also zero-initializes the fallback counter in d_out.
// ---------------------------------------------------------------------------
__global__ void gating_prepack(const float* __restrict__ sim,
                               unsigned short* __restrict__ Bpk,
                               float* __restrict__ out) {
    int tid = blockIdx.x * 256 + threadIdx.x;
    if (tid == 0) out[FB_OFF] = 0.0f;
    if (tid >= C_DIM * E_DIM) return;
    int k = tid >> 6;
    int e = tid & 63;
    float v = sim[tid];                       // sim[k*64 + e]
    unsigned short hi = f2bf_rtn(v);
    float hif = __uint_as_float(((unsigned)hi) << 16);
    unsigned short lo = f2bf_rtn(v - hif);
    int s  = k >> 6;
    int kk = (k >> 5) & 1;
    int gr = (k >> 3) & 3;
    int i  = k & 7;
    int lane = gr * 16 + (e & 15);
    int nb   = e >> 4;
    int base = s * 8192 + ((kk * 2 + 0) * 4 + nb) * 512 + lane * 8 + i;
    Bpk[base]        = hi;   // hl = 0
    Bpk[base + 2048] = lo;   // hl = 1 -> +4*512 shorts
}

// ---------------------------------------------------------------------------
// Kernel 2: fused affinity-GEMM (split-bf16 MFMA) + gating epilogue.
// Grid 1024 x 256 (4 waves). Block owns 16 tokens; wave w computes the
// K-quarter w*512..w*512+511 (8 stages of 64), accumulators reduced across
// waves via LDS. No barriers in the K-loop; B read directly from L2-resident
// prepacked buffer (512 KB). Wave w finishes tokens with C/D reg r = w.
// ---------------------------------------------------------------------------
__global__ __launch_bounds__(256, 4)
void gating_main(const float* __restrict__ x,
                 const unsigned short* __restrict__ Bpk,
                 const float* __restrict__ gates,
                 float* __restrict__ out) {
    __shared__ float red[4][16][64];   // [wave][nb*4+r][lane] = 16 KB

    const int tid = threadIdx.x;
    const int l   = tid & 63;
    const int w   = tid >> 6;          // wave id == K-split index == C/D reg r
    const int blk = blockIdx.x;
    const int row0 = blk * 16;
    const int g    = l >> 4;           // k-slot group / token subgroup
    const int e0   = l & 15;
    const float* xr = x + (size_t)(row0 + e0) * C_DIM + w * 512;
    const unsigned short* bw = Bpk + w * 8 * 8192;

    f32x4 acc[4];
#pragma unroll
    for (int nb = 0; nb < 4; ++nb) acc[nb] = (f32x4)0.0f;

    for (int s = 0; s < 8; ++s) {
#pragma unroll
        for (int kk = 0; kk < 2; ++kk) {
            const float* ap = xr + s * 64 + kk * 32 + g * 8;
            float4 a0 = *(const float4*)ap;
            float4 a1 = *(const float4*)(ap + 4);
            float av[8] = {a0.x, a0.y, a0.z, a0.w, a1.x, a1.y, a1.z, a1.w};
            bf16x8 ah, al_;
#pragma unroll
            for (int i = 0; i < 8; ++i) {
                unsigned short h = f2bf_rtn(av[i]);
                float hf = __uint_as_float(((unsigned)h) << 16);
                unsigned short lo = f2bf_rtn(av[i] - hf);
                ah[i]  = (short)h;
                al_[i] = (short)lo;
            }
            const unsigned short* bs = bw + s * 8192 + kk * 4096 + l * 8;
#pragma unroll
            for (int nb = 0; nb < 4; ++nb) {
                bf16x8 bh = *(const bf16x8*)(bs + nb * 512);
                bf16x8 bl = *(const bf16x8*)(bs + 2048 + nb * 512);
                acc[nb] = __builtin_amdgcn_mfma_f32_16x16x32_bf16(ah, bh, acc[nb], 0, 0, 0);
                acc[nb] = __builtin_amdgcn_mfma_f32_16x16x32_bf16(ah, bl, acc[nb], 0, 0, 0);
                acc[nb] = __builtin_amdgcn_mfma_f32_16x16x32_bf16(al_, bh, acc[nb], 0, 0, 0);
            }
        }
    }

    // ---- cross-wave K reduction via LDS (conflict-free layout) ----
#pragma unroll
    for (int nb = 0; nb < 4; ++nb)
#pragma unroll
        for (int r = 0; r < 4; ++r)
            red[w][nb * 4 + r][l] = acc[nb][r];
    __syncthreads();

    float tot[4];
#pragma unroll
    for (int nb = 0; nb < 4; ++nb)
        tot[nb] = red[0][nb * 4 + w][l] + red[1][nb * 4 + w][l]
                + red[2][nb * 4 + w][l] + red[3][nb * 4 + w][l];

    // ---- epilogue: wave w handles tokens t = row0 + g*4 + w ----
    float sig[4];
#pragma unroll
    for (int nb = 0; nb < 4; ++nb)
        sig[nb] = 1.0f / (1.0f + expf(-gates[nb * 16 + e0]));

    const int t = row0 + g * 4 + w;
    float lg[4];
    bool  act[4];
    int   lcnt = 0;
    float lmax = -3.4e38f;
#pragma unroll
    for (int nb = 0; nb < 4; ++nb) {
        lg[nb]  = tot[nb] - sig[nb];
        act[nb] = lg[nb] > 0.0f;
        if (act[nb]) { lcnt++; lmax = fmaxf(lmax, lg[nb]); }
    }
    int cnt = lcnt;
    float mx = lmax;
#pragma unroll
    for (int m = 1; m < 16; m <<= 1) {
        cnt += __shfl_xor(cnt, m, 16);
        mx   = fmaxf(mx, __shfl_xor(mx, m, 16));
    }

    float p[4], am[4];
    if (cnt > 0) {
        float ex[4], ls = 0.0f;
#pragma unroll
        for (int nb = 0; nb < 4; ++nb) {
            ex[nb] = act[nb] ? expf(lg[nb] - mx) : 0.0f;
            ls += ex[nb];
        }
        float Z = ls;
#pragma unroll
        for (int m = 1; m < 16; m <<= 1) Z += __shfl_xor(Z, m, 16);
        float rz = 1.0f / Z;
#pragma unroll
        for (int nb = 0; nb < 4; ++nb) {
            p[nb]  = ex[nb] * rz;
            am[nb] = act[nb] ? 1.0f : 0.0f;
        }
    } else {
        // fallback: top-32 of the 64 logits (ties -> lower expert index).
        // All logits <= 0 here, so probs are uniform 1/32 over the set.
        unsigned selm = 0;
        for (int it = 0; it < 32; ++it) {
            float bv = -3.4e38f;
            int   bi = 127;
#pragma unroll
            for (int nb = 0; nb < 4; ++nb) {
                if (!((selm >> nb) & 1)) {
                    float v = lg[nb];
                    int   e = nb * 16 + e0;
                    if (v > bv || (v == bv && e < bi)) { bv = v; bi = e; }
                }
            }
#pragma unroll
            for (int m = 1; m < 16; m <<= 1) {
                float ov = __shfl_xor(bv, m, 16);
                int   oi = __shfl_xor(bi, m, 16);
                if (ov > bv || (ov == bv && oi < bi)) { bv = ov; bi = oi; }
            }
            if ((bi & 15) == e0) selm |= 1u << (bi >> 4);
        }
#pragma unroll
        for (int nb = 0; nb < 4; ++nb) {
            bool s_ = (selm >> nb) & 1;
            p[nb]  = s_ ? (1.0f / 32.0f) : 0.0f;
            am[nb] = s_ ? 1.0f : 0.0f;
        }
        if (e0 == 0) atomicAdd(&out[FB_OFF], 1.0f);
    }

#pragma unroll
    for (int nb = 0; nb < 4; ++nb) {
        int idx = t * 64 + nb * 16 + e0;
        out[idx]          = p[nb];
        out[LG_OFF + idx] = lg[nb];
        out[AM_OFF + idx] = am[nb];
    }
}

// ---------------------------------------------------------------------------
extern "C" void kernel_launch(void* const* d_in, const int* in_sizes, int n_in,
                              void* d_out, int out_size, void* d_ws, size_t ws_size,
                              hipStream_t stream) {
    const float* x     = (const float*)d_in[0];   // [4,4096,2048] f32
    const float* sim   = (const float*)d_in[1];   // [2048,64] f32
    const float* gates = (const float*)d_in[2];   // [64] f32
    float* out = (float*)d_out;
    unsigned short* Bpk = (unsigned short*)d_ws;  // 512 KB prepacked B (hi/lo)

    gating_prepack<<<512, 256, 0, stream>>>(sim, Bpk, out);
    gating_main<<<1024, 256, 0, stream>>>(x, Bpk, gates, out);
}